// Round 3
// baseline (111.568 us; speedup 1.0000x reference)
//
#include <hip/hip_runtime.h>

typedef __bf16 bf16x8 __attribute__((ext_vector_type(8)));
typedef float f32x16 __attribute__((ext_vector_type(16)));

#define TWO_LOG2E 2.88539008177792681f   // 2*log2(e): exp(2x) = exp2(x*TWO_LOG2E)

#define GLOADLDS16(g, l) __builtin_amdgcn_global_load_lds(                     \
    (const __attribute__((address_space(1))) void*)(g),                        \
    (__attribute__((address_space(3))) void*)(l), 16, 0, 0)

__device__ __forceinline__ unsigned f2bf(float f) {
    unsigned u = __float_as_uint(f);
    return (u + 0x7FFFu + ((u >> 16) & 1u)) >> 16;   // RNE
}

// ---------------- kernel 1: row-normalize z=[z1;z2] -> bf16 zn[8192][256] ---------------
// Blocks 0..31 also zero S[8192]; block 32 zeroes out[0]. (R10-proven form.)
__global__ void __launch_bounds__(256) normalize_kernel(
    const float* __restrict__ z1, const float* __restrict__ z2,
    unsigned short* __restrict__ zn, float* __restrict__ S, float* __restrict__ out)
{
    if (blockIdx.x < 32) S[(blockIdx.x << 8) + threadIdx.x] = 0.f;
    if (blockIdx.x == 32 && threadIdx.x == 0) out[0] = 0.f;

    const int wave = threadIdx.x >> 6, lane = threadIdx.x & 63;
    const int row = (blockIdx.x << 2) + wave;               // 2048 blocks * 4 rows
    const float* src = (row < 4096) ? (z1 + row * 256) : (z2 + (row - 4096) * 256);
    float4 v = ((const float4*)src)[lane];                  // 64 lanes * 4 = 256
    float ss = v.x * v.x + v.y * v.y + v.z * v.z + v.w * v.w;
#pragma unroll
    for (int m = 32; m > 0; m >>= 1) ss += __shfl_xor(ss, m, 64);
    float sc = 1.0f / fmaxf(sqrtf(ss), 1e-8f);
    uint2 w;
    w.x = f2bf(v.x * sc) | (f2bf(v.y * sc) << 16);
    w.y = f2bf(v.z * sc) | (f2bf(v.w * sc) << 16);
    *(uint2*)(zn + row * 256 + (lane << 2)) = w;
}

// ---------------- kernel 2: 4-wave shared-B ring, 32x32x16 MFMA, lane-linear LDS -------
// Block = 128 rows x 512 cols (1024 blocks), wave owns 32 rows. Chunk = 32 cols x 64 k
// (4 KB), ring of 4, depth-2 prefetch: per interval each wave stages 1/4 of chunk m+2
// (one global_load_lds dwordx4), waits counted `s_waitcnt vmcnt(2)` (its quarter of
// chunk m complete), then raw s_barrier publishes chunk m. NEVER __syncthreads (drains
// vmcnt(0)). Write-after-read safe: buffer m&3 is consumed at interval m and re-staged
// by a stage issued at interval m+2, after barrier m+1 which all waves pass only after
// their chunk-m ds_reads are lgkm-retired (MFMA operand waits precede the barrier).
//
// LDS chunk layout [kslot s=0..7][col c=0..31] of 16B tiles (s*512 + c*16 bytes):
//  - stage:   lane-linear destination, source zn[colBase + (i&31)][K0 + (i>>5)*8 ..+7]
//  - consume: MFMA kk reads slot kk*2+h (h=lane>>5), col lane&31 -> the full wave reads
//    one contiguous 1KB line per ds_read_b128: stride-1, zero bank conflicts, no swizzle.
// Fragments (mfma_f32_32x32x16_bf16): A row=lane&31,k=h*8+e; B col=lane&31,k=h*8+e;
// C/D col=lane&31, row=(reg&3)+8*(reg>>2)+4*h.
__global__ void __launch_bounds__(256, 4) simexp_kernel(
    const unsigned short* __restrict__ zn, float* __restrict__ S)
{
    __shared__ __align__(16) unsigned short Bs[4][2048];    // 4 x 4KB ring, block-shared

    const int tid = threadIdx.x;
    const int wv = tid >> 6, lane = tid & 63;
    const int h = lane >> 5, c32 = lane & 31;
    const int job = blockIdx.x;                 // 0..1023
    const int rowBase = (job >> 4) << 7;        // strip * 128
    const int colRun  = (job & 15) << 9;        // run * 512
    const int rowW = rowBase + (wv << 5);       // this wave's 32 rows

    // A: 32 rows x K=256 in registers: a[f] covers k = f*16 + h*8 + [0..7]
    bf16x8 a[16];
#pragma unroll
    for (int f = 0; f < 16; ++f)
        a[f] = *(const bf16x8*)(zn + ((rowW + c32) << 8) + (f << 4) + (h << 3));

    // stage this wave's quarter of chunk m (col-chunk m>>2, k-chunk m&3)
    auto stage = [&](int m) {
        const int colBase = colRun + ((m >> 2) << 5);
        const int K0 = (m & 3) << 6;
        unsigned short* base = &Bs[m & 3][0];
        int i = (wv << 6) + lane;               // 16B slot 0..255; s = i>>5, c = i&31
        GLOADLDS16(zn + ((colBase + (i & 31)) << 8) + K0 + ((i >> 5) << 3),
                   base + (i << 3));
    };

    float rs[16];
#pragma unroll
    for (int i = 0; i < 16; ++i) rs[i] = 0.f;

    f32x16 acc;
    // consume chunk in buffer Bs[kc] (kc = k-chunk = m&3, compile-time via unroll)
    auto consume = [&](int kc) {
        const unsigned short* bb = &Bs[kc & 3][0];
#pragma unroll
        for (int kk = 0; kk < 4; ++kk) {
            // slot = kk*2 + h, elem offset = slot*256 + c*8 -> contiguous 1KB per wave
            bf16x8 bf = *(const bf16x8*)(bb + (((kk << 1) + h) << 8) + (c32 << 3));
            acc = __builtin_amdgcn_mfma_f32_32x32x16_bf16(
                a[(kc << 2) + kk], bf, acc, 0, 0, 0);
        }
    };
    auto zacc = [&]() {
#pragma unroll
        for (int i = 0; i < 16; ++i) acc[i] = 0.f;
    };
    auto epilogue = [&]() {
#pragma unroll
        for (int r = 0; r < 16; ++r)
            rs[r] += __builtin_amdgcn_exp2f(acc[r] * TWO_LOG2E);
    };

    stage(0);
    stage(1);

    for (int cc = 0; cc < 15; ++cc) {            // main: chunks m=cc*4+kc, stage m+2
        zacc();
#pragma unroll
        for (int kc = 0; kc < 4; ++kc) {
            stage((cc << 2) + kc + 2);
            asm volatile("s_waitcnt vmcnt(2)" ::: "memory");
            __builtin_amdgcn_s_barrier();
            asm volatile("" ::: "memory");       // keep ds_reads below the barrier
            consume(kc);
        }
        epilogue();
    }
    // peeled tail cc=15: chunks 60..63 (stage 62,63 then drain 1->0)
    zacc();
    stage(62);
    asm volatile("s_waitcnt vmcnt(2)" ::: "memory");
    __builtin_amdgcn_s_barrier();
    asm volatile("" ::: "memory");
    consume(0);
    stage(63);
    asm volatile("s_waitcnt vmcnt(2)" ::: "memory");
    __builtin_amdgcn_s_barrier();
    asm volatile("" ::: "memory");
    consume(1);
    asm volatile("s_waitcnt vmcnt(1)" ::: "memory");
    __builtin_amdgcn_s_barrier();
    asm volatile("" ::: "memory");
    consume(2);
    asm volatile("s_waitcnt vmcnt(0)" ::: "memory");
    __builtin_amdgcn_s_barrier();
    asm volatile("" ::: "memory");
    consume(3);
    epilogue();

    // flush once per wave (C/D: col=lane&31, row=(r&3)+8*(r>>2)+4*h)
#pragma unroll
    for (int r = 0; r < 16; ++r) {
        float s = rs[r];
        s += __shfl_xor(s, 1, 64);
        s += __shfl_xor(s, 2, 64);
        s += __shfl_xor(s, 4, 64);
        s += __shfl_xor(s, 8, 64);
        s += __shfl_xor(s, 16, 64);
        if (c32 == 0)
            atomicAdd(&S[rowW + (r & 3) + ((r >> 2) << 3) + (h << 2)], s);
    }
}

// ---------------- kernel 3: loss = mean( log(S_i - e^{sim_ii}) - sim_{i,target} ) -------
__global__ void __launch_bounds__(256) finish_kernel(
    const unsigned short* __restrict__ zn, const float* __restrict__ S,
    float* __restrict__ out)
{
    __shared__ float vals[16];
    const int tid = threadIdx.x, lane = tid & 63, wave = tid >> 6;
    const int q = lane >> 4, n16 = lane & 15;
    const int rib = (wave << 2) + q;                // 0..15 rows per block
    const int row = (blockIdx.x << 4) + rib;        // 512 blocks * 16 rows
    const int tar = (row + 4096) & 8191;

    float drr = 0.f, drt = 0.f;
#pragma unroll
    for (int i = 0; i < 4; ++i) {
        int k = (i << 6) + (n16 << 2);
        uint2 ur = *(const uint2*)(zn + (row << 8) + k);
        uint2 ut = *(const uint2*)(zn + (tar << 8) + k);
        float a0 = __uint_as_float(ur.x << 16),  a1 = __uint_as_float(ur.x & 0xFFFF0000u);
        float a2 = __uint_as_float(ur.y << 16),  a3 = __uint_as_float(ur.y & 0xFFFF0000u);
        float b0 = __uint_as_float(ut.x << 16),  b1 = __uint_as_float(ut.x & 0xFFFF0000u);
        float b2 = __uint_as_float(ut.y << 16),  b3 = __uint_as_float(ut.y & 0xFFFF0000u);
        drr += a0 * a0 + a1 * a1 + a2 * a2 + a3 * a3;
        drt += a0 * b0 + a1 * b1 + a2 * b2 + a3 * b3;
    }
#pragma unroll
    for (int m = 1; m <= 8; m <<= 1) {
        drr += __shfl_xor(drr, m, 64);
        drt += __shfl_xor(drt, m, 64);
    }
    if (n16 == 0) {
        float Sv = S[row] - __builtin_amdgcn_exp2f(drr * TWO_LOG2E);  // remove diagonal
        vals[rib] = 0.693147180559945f * __builtin_amdgcn_logf(Sv) - 2.0f * drt;
    }
    __syncthreads();
    if (tid == 0) {
        float s = 0.f;
#pragma unroll
        for (int i = 0; i < 16; ++i) s += vals[i];
        atomicAdd(out, s * (1.0f / 8192.0f));
    }
}

extern "C" void kernel_launch(void* const* d_in, const int* in_sizes, int n_in,
                              void* d_out, int out_size, void* d_ws, size_t ws_size,
                              hipStream_t stream)
{
    const float* z1 = (const float*)d_in[0];
    const float* z2 = (const float*)d_in[1];
    unsigned short* zn = (unsigned short*)d_ws;                              // 4 MB
    float* S = (float*)((char*)d_ws + 8192 * 256 * sizeof(unsigned short));  // 32 KB
    float* out = (float*)d_out;

    normalize_kernel<<<2048, 256, 0, stream>>>(z1, z2, zn, S, out);
    simexp_kernel<<<1024, 256, 0, stream>>>(zn, S);
    finish_kernel<<<512, 256, 0, stream>>>(zn, S, out);
}

// Round 4
// 101.641 us; speedup vs baseline: 1.0977x; 1.0977x over previous
//
#include <hip/hip_runtime.h>

typedef __bf16 bf16x8 __attribute__((ext_vector_type(8)));
typedef float f32x4 __attribute__((ext_vector_type(4)));

#define TWO_LOG2E 2.88539008177792681f   // 2*log2(e): exp(2x) = exp2(x*TWO_LOG2E)

#define GLOADLDS16(g, l) __builtin_amdgcn_global_load_lds(                     \
    (const __attribute__((address_space(1))) void*)(g),                        \
    (__attribute__((address_space(3))) void*)(l), 16, 0, 0)

__device__ __forceinline__ unsigned f2bf(float f) {
    unsigned u = __float_as_uint(f);
    return (u + 0x7FFFu + ((u >> 16) & 1u)) >> 16;   // RNE
}

// ---------------- kernel 1: row-normalize z=[z1;z2] -> bf16 zn[8192][256] ---------------
// Blocks 0..31 also zero S[8192]; block 32 zeroes out[0]. (R10-proven form.)
__global__ void __launch_bounds__(256) normalize_kernel(
    const float* __restrict__ z1, const float* __restrict__ z2,
    unsigned short* __restrict__ zn, float* __restrict__ S, float* __restrict__ out)
{
    if (blockIdx.x < 32) S[(blockIdx.x << 8) + threadIdx.x] = 0.f;
    if (blockIdx.x == 32 && threadIdx.x == 0) out[0] = 0.f;

    const int wave = threadIdx.x >> 6, lane = threadIdx.x & 63;
    const int row = (blockIdx.x << 2) + wave;               // 2048 blocks * 4 rows
    const float* src = (row < 4096) ? (z1 + row * 256) : (z2 + (row - 4096) * 256);
    float4 v = ((const float4*)src)[lane];                  // 64 lanes * 4 = 256
    float ss = v.x * v.x + v.y * v.y + v.z * v.z + v.w * v.w;
#pragma unroll
    for (int m = 32; m > 0; m >>= 1) ss += __shfl_xor(ss, m, 64);
    float sc = 1.0f / fmaxf(sqrtf(ss), 1e-8f);
    uint2 w;
    w.x = f2bf(v.x * sc) | (f2bf(v.y * sc) << 16);
    w.y = f2bf(v.z * sc) | (f2bf(v.w * sc) << 16);
    *(uint2*)(zn + row * 256 + (lane << 2)) = w;
}

// ---------------- kernel 2: 8-wave 256x512 tile, XCD-pinned runs, parity staging -------
// Grid 512 blocks x 512 thr. Block = 256 rows x 512 cols -> B traffic halves vs the
// 128-row strip (32 strips * 4MB = 128MB; +A 64MB = 192MB total, was 320MB).
// XCD pinning: with round-robin block->XCD dispatch, run = (bid&7)*2 + ((bid>>3)&1)
// gives each XCD exactly 2 col-runs (B-panel 512KB, L2-resident) and all 64 of its
// blocks co-resident (2 blocks/CU x 32 CU) -> B re-reads are local-L2 hits, not L3.
// Perf heuristic only; correctness does not depend on the mapping.
//
// Staging (R1-proven geometry, 128B-contiguous transactions -- R3's lane-linear layout
// regressed 8us from 16-32B scattered transactions, do NOT repeat): chunk = 32 cols x
// 64 k (4KB), ring of 4, depth-2. Wave-group g = wv>>2 stages chunks of parity g (one
// global_load_lds dwordx4 per staging wave, wl=wv&3 picks its quarter); the staging
// group waits counted `s_waitcnt vmcnt(1)` (own chunk-m load complete, chunk-m+2 still
// in flight), then raw s_barrier publishes chunk m to all 8 waves. NEVER __syncthreads
// (drains vmcnt(0)). WAR-safe: buffer m&3 (rewritten by stage(m+2) issued at interval
// m) was read at consume(m-2), whose ds_reads precede barrier(m-1), which precedes the
// restage -- barrier-ordered, the discipline that has passed absmax=0.0 since R1.
__global__ void __launch_bounds__(512, 4) simexp_kernel(
    const unsigned short* __restrict__ zn, float* __restrict__ S)
{
    __shared__ __align__(16) unsigned short Bs[4][2048];    // 4 x 4KB ring, block-shared

    const int tid = threadIdx.x;
    const int wv = tid >> 6, lane = tid & 63;
    const int q = lane >> 4, n16 = lane & 15;
    const int g = wv >> 2, wl = wv & 3;         // staging group / quarter within group
    const int bid = blockIdx.x;                 // 0..511
    const int run   = ((bid & 7) << 1) | ((bid >> 3) & 1);  // 0..15, 2 runs per XCD
    const int strip = bid >> 4;                 // 0..31
    const int rowBase = strip << 8;             // strip * 256
    const int colRun  = run << 9;               // run * 512
    const int rowW = rowBase + (wv << 5);       // this wave's 32 rows

    // A: 32 rows x K=256 in registers (frag: row=n16, k=q*8 within 32-elem step)
    bf16x8 a[2][8];
#pragma unroll
    for (int rt = 0; rt < 2; ++rt)
#pragma unroll
        for (int ks = 0; ks < 8; ++ks)
            a[rt][ks] = *(const bf16x8*)(zn + ((rowW + (rt << 4) + n16) << 8)
                                            + (ks << 5) + (q << 3));

    // stage this wave's quarter of chunk m (col-chunk m>>2, k-chunk m&3); 128B rows
    auto stage = [&](int m) {
        const int colBase = colRun + ((m >> 2) << 5);
        const int koff = (m & 3) << 6;
        unsigned short* base = &Bs[m & 3][0];
        int s = (wl << 6) + lane;               // 16B slot 0..255
        int c = s >> 3, d = s & 7;              // 8 consecutive lanes per row -> 128B
        int k8 = d ^ (c & 7);                   // XOR swizzle (conflict-free b128 reads)
        GLOADLDS16(zn + ((colBase + c) << 8) + koff + (k8 << 3), base + (s << 3));
    };

    float rs[2][4];
#pragma unroll
    for (int i = 0; i < 2; ++i)
#pragma unroll
        for (int j = 0; j < 4; ++j) rs[i][j] = 0.f;

    f32x4 acc[2][2];
    // consume chunk in buffer Bs[kc] using a-step (kc*2+ks); kc is compile-time
    auto consume = [&](int kc) {
        const unsigned short* bb = &Bs[kc & 3][0];
#pragma unroll
        for (int ks = 0; ks < 2; ++ks) {
            bf16x8 bf[2];
#pragma unroll
            for (int ct = 0; ct < 2; ++ct) {
                int c  = (ct << 4) + n16;               // col 0..31
                int k8 = ((ks << 2) + q) ^ (c & 7);     // swizzled chunk
                bf[ct] = *(const bf16x8*)(bb + (((c << 3) + k8) << 3));
            }
#pragma unroll
            for (int rt = 0; rt < 2; ++rt)
#pragma unroll
                for (int ct = 0; ct < 2; ++ct)
                    acc[rt][ct] = __builtin_amdgcn_mfma_f32_16x16x32_bf16(
                        a[rt][(kc << 1) + ks], bf[ct], acc[rt][ct], 0, 0, 0);
        }
    };
    auto zacc = [&]() {
#pragma unroll
        for (int rt = 0; rt < 2; ++rt)
#pragma unroll
            for (int ct = 0; ct < 2; ++ct) acc[rt][ct] = (f32x4){0.f, 0.f, 0.f, 0.f};
    };
    auto epilogue = [&]() {
#pragma unroll
        for (int rt = 0; rt < 2; ++rt)
#pragma unroll
            for (int ct = 0; ct < 2; ++ct)
#pragma unroll
                for (int r = 0; r < 4; ++r)
                    rs[rt][r] += __builtin_amdgcn_exp2f(acc[rt][ct][r] * TWO_LOG2E);
    };

    // prologue: group 0 stages chunk 0, group 1 stages chunk 1
    if (g == 0) stage(0); else stage(1);

    for (int cc = 0; cc < 15; ++cc) {            // intervals m=cc*4+kc; parity = kc&1
        zacc();
#pragma unroll
        for (int kc = 0; kc < 4; ++kc) {
            if ((kc & 1) == g) {                 // wave-uniform branch
                stage((cc << 2) + kc + 2);
                asm volatile("s_waitcnt vmcnt(1)" ::: "memory");  // own chunk-m done
            }
            __builtin_amdgcn_s_barrier();
            asm volatile("" ::: "memory");       // keep ds_reads below the barrier
            consume(kc);
        }
        epilogue();
    }
    // peeled tail cc=15: chunks 60..63 (stage 62 by g0, 63 by g1, then drain)
    zacc();
    if (g == 0) { stage(62); asm volatile("s_waitcnt vmcnt(1)" ::: "memory"); }
    __builtin_amdgcn_s_barrier();
    asm volatile("" ::: "memory");
    consume(0);
    if (g == 1) { stage(63); asm volatile("s_waitcnt vmcnt(1)" ::: "memory"); }
    __builtin_amdgcn_s_barrier();
    asm volatile("" ::: "memory");
    consume(1);
    if (g == 0) { asm volatile("s_waitcnt vmcnt(0)" ::: "memory"); }
    __builtin_amdgcn_s_barrier();
    asm volatile("" ::: "memory");
    consume(2);
    if (g == 1) { asm volatile("s_waitcnt vmcnt(0)" ::: "memory"); }
    __builtin_amdgcn_s_barrier();
    asm volatile("" ::: "memory");
    consume(3);
    epilogue();

    // flush once per wave (C/D layout: col=n16, row=q*4+r)
#pragma unroll
    for (int rt = 0; rt < 2; ++rt)
#pragma unroll
        for (int r = 0; r < 4; ++r) {
            float s = rs[rt][r];
            s += __shfl_xor(s, 1, 64);
            s += __shfl_xor(s, 2, 64);
            s += __shfl_xor(s, 4, 64);
            s += __shfl_xor(s, 8, 64);
            if (n16 == 0) atomicAdd(&S[rowW + (rt << 4) + (q << 2) + r], s);
        }
}

// ---------------- kernel 3: loss = mean( log(S_i - e^{sim_ii}) - sim_{i,target} ) -------
__global__ void __launch_bounds__(256) finish_kernel(
    const unsigned short* __restrict__ zn, const float* __restrict__ S,
    float* __restrict__ out)
{
    __shared__ float vals[16];
    const int tid = threadIdx.x, lane = tid & 63, wave = tid >> 6;
    const int q = lane >> 4, n16 = lane & 15;
    const int rib = (wave << 2) + q;                // 0..15 rows per block
    const int row = (blockIdx.x << 4) + rib;        // 512 blocks * 16 rows
    const int tar = (row + 4096) & 8191;

    float drr = 0.f, drt = 0.f;
#pragma unroll
    for (int i = 0; i < 4; ++i) {
        int k = (i << 6) + (n16 << 2);
        uint2 ur = *(const uint2*)(zn + (row << 8) + k);
        uint2 ut = *(const uint2*)(zn + (tar << 8) + k);
        float a0 = __uint_as_float(ur.x << 16),  a1 = __uint_as_float(ur.x & 0xFFFF0000u);
        float a2 = __uint_as_float(ur.y << 16),  a3 = __uint_as_float(ur.y & 0xFFFF0000u);
        float b0 = __uint_as_float(ut.x << 16),  b1 = __uint_as_float(ut.x & 0xFFFF0000u);
        float b2 = __uint_as_float(ut.y << 16),  b3 = __uint_as_float(ut.y & 0xFFFF0000u);
        drr += a0 * a0 + a1 * a1 + a2 * a2 + a3 * a3;
        drt += a0 * b0 + a1 * b1 + a2 * b2 + a3 * b3;
    }
#pragma unroll
    for (int m = 1; m <= 8; m <<= 1) {
        drr += __shfl_xor(drr, m, 64);
        drt += __shfl_xor(drt, m, 64);
    }
    if (n16 == 0) {
        float Sv = S[row] - __builtin_amdgcn_exp2f(drr * TWO_LOG2E);  // remove diagonal
        vals[rib] = 0.693147180559945f * __builtin_amdgcn_logf(Sv) - 2.0f * drt;
    }
    __syncthreads();
    if (tid == 0) {
        float s = 0.f;
#pragma unroll
        for (int i = 0; i < 16; ++i) s += vals[i];
        atomicAdd(out, s * (1.0f / 8192.0f));
    }
}

extern "C" void kernel_launch(void* const* d_in, const int* in_sizes, int n_in,
                              void* d_out, int out_size, void* d_ws, size_t ws_size,
                              hipStream_t stream)
{
    const float* z1 = (const float*)d_in[0];
    const float* z2 = (const float*)d_in[1];
    unsigned short* zn = (unsigned short*)d_ws;                              // 4 MB
    float* S = (float*)((char*)d_ws + 8192 * 256 * sizeof(unsigned short));  // 32 KB
    float* out = (float*)d_out;

    normalize_kernel<<<2048, 256, 0, stream>>>(z1, z2, zn, S, out);
    simexp_kernel<<<512, 512, 0, stream>>>(zn, S);
    finish_kernel<<<512, 256, 0, stream>>>(zn, S, out);
}